// Round 5
// baseline (360.246 us; speedup 1.0000x reference)
//
#include <hip/hip_runtime.h>
#include <math.h>

// Problem constants (reference: B=32, P=256, D=64, T=4096, SCALE=1)
#define Bb 32
#define Pp 256
#define Dd 64
#define Tt 4096

// kernel1: one wave per (batch, 64-task chunk). 64 chunks/batch x 32 b -> 2048
// waves = exactly 2 waves/SIMD at __launch_bounds__(256,2) (VGPR cap 256).
//
// Register-residency history:
//   R1 default bounds, no pin:        W re-fetched from L2 every p  -> 230 us.
//   R2/R4 pin OUTSIDE p-loop:         W still LOOP-INVARIANT -> RA spilled it
//        to scratch (VGPR stayed 48, VALUBusy 19%, 275 us). Lesson: RA only
//        reliably keeps LOOP-CARRIED values resident.
//   R5 (this): pin INSIDE the p-loop body -> each iteration redefines w from
//        the previous one -> loop-carried, non-remat; spill would cost a
//        per-iteration reload, so RA keeps it in VGPRs (cap has room: ~110).
//   R3 NaN lesson: per-step EXACT wave max is required (scores drop ~32/step;
//        any stale shift underflows e^{c-m} on ALL lanes -> S=0 -> NaN).
//
// Data row is wave-uniform -> compiler scalarizes to s_load (SGPR=80 in R4
// confirms); unroll 1 keeps one 64-SGPR row within the 102-SGPR budget.
// ws layout: float4 (m, s, v, pad) at [((b*P + p)*64 + chunk)] -> 8.4 MB.
__global__ __launch_bounds__(256, 2) void k_scan(const float* __restrict__ data,
                                                 const float* __restrict__ targets,
                                                 const float* __restrict__ task_pool,
                                                 float4* __restrict__ ws) {
  const int b     = blockIdx.x >> 4;          // 16 blocks per batch
  const int wid   = threadIdx.x >> 6;
  const int lane  = threadIdx.x & 63;
  const int chunk = ((blockIdx.x & 15) << 2) | wid;   // 0..63
  const int t     = (chunk << 6) | lane;              // this lane's task

  // W column for task t: load once before the loop.
  float w[Dd];
#pragma unroll
  for (int d = 0; d < Dd; d += 4) {
    const float4 r = *(const float4*)(task_pool + (size_t)t * Dd + d);
    w[d] = r.x; w[d + 1] = r.y; w[d + 2] = r.z; w[d + 3] = r.w;
  }

  const float* __restrict__ drow = data + (size_t)b * (Pp * Dd);  // wave-uniform
  const float* __restrict__ tgt  = targets + b * Pp;
  float4* __restrict__ wsb       = ws + (size_t)b * (Pp * 64);

  float c = 0.f;  // cumulative score (loglik prefix) for this lane's task
#pragma unroll 1
  for (int p = 0; p < Pp; ++p) {
    // THE pin: inside the loop, so w is loop-carried (see header comment).
#pragma unroll
    for (int d = 0; d < Dd; ++d) asm volatile("" : "+v"(w[d]));

    // pred = data[b,p,:] . W[:,t]; row address is wave-uniform -> s_load.
    float a0 = 0.f, a1 = 0.f, a2 = 0.f, a3 = 0.f;
    const float* __restrict__ r = drow + p * Dd;
#pragma unroll
    for (int d = 0; d < Dd; d += 4) {
      a0 = fmaf(r[d],     w[d],     a0);
      a1 = fmaf(r[d + 1], w[d + 1], a1);
      a2 = fmaf(r[d + 2], w[d + 2], a2);
      a3 = fmaf(r[d + 3], w[d + 3], a3);
    }
    const float pred = (a0 + a1) + (a2 + a3);

    // exact per-step wave max of c (uses prefix through p-1; p=0 -> uniform)
    float m = c;
#pragma unroll
    for (int off = 32; off; off >>= 1) m = fmaxf(m, __shfl_xor(m, off, 64));
    const float e = __expf(c - m);   // in (0,1], ==1 at the max lane
    float s = e, v = e * pred;
#pragma unroll
    for (int off = 32; off; off >>= 1) {
      s += __shfl_xor(s, off, 64);
      v += __shfl_xor(v, off, 64);
    }
    if (lane == 0) wsb[p * 64 + chunk] = make_float4(m, s, v, 0.f);

    // score update AFTER emitting the prefix posterior (log_norm const drops out)
    const float err = tgt[p] - pred;
    c = fmaf(-0.5f * err, err, c);
  }
}

// kernel2: one wave per (b,p); exact merge of the 64 chunk triples.
// value represented by a triple is e^m * (s, v); merge with global shift M.
__global__ __launch_bounds__(256) void k_merge(const float4* __restrict__ ws,
                                               float* __restrict__ out) {
  const int gt   = blockIdx.x * 256 + threadIdx.x;
  const int bp   = gt >> 6;   // b*P + p
  const int lane = gt & 63;   // chunk id
  const float4 o = ws[(size_t)bp * 64 + lane];
  const float m = o.x, s = o.y, v = o.z;
  float M = m;
#pragma unroll
  for (int off = 32; off; off >>= 1) M = fmaxf(M, __shfl_xor(M, off, 64));
  const float f = __expf(m - M);
  float S = f * s, V = f * v;
#pragma unroll
  for (int off = 32; off; off >>= 1) {
    S += __shfl_xor(S, off, 64);
    V += __shfl_xor(V, off, 64);
  }
  if (lane == 0) out[bp] = V / S;
}

extern "C" void kernel_launch(void* const* d_in, const int* in_sizes, int n_in,
                              void* d_out, int out_size, void* d_ws, size_t ws_size,
                              hipStream_t stream) {
  const float* data      = (const float*)d_in[0];
  const float* targets   = (const float*)d_in[1];
  const float* task_pool = (const float*)d_in[2];
  float* out = (float*)d_out;
  float4* ws = (float4*)d_ws;  // needs 32*256*64*16 B = 8.4 MB

  k_scan<<<dim3(512), dim3(256), 0, stream>>>(data, targets, task_pool, ws);
  k_merge<<<dim3((Bb * Pp * 64) / 256), dim3(256), 0, stream>>>(ws, out);
}

// Round 6
// 244.762 us; speedup vs baseline: 1.4718x; 1.4718x over previous
//
#include <hip/hip_runtime.h>
#include <math.h>

// Problem constants (reference: B=32, P=256, D=64, T=4096, SCALE=1)
#define Bb 32
#define Pp 256
#define Dd 64
#define Tt 4096

#define PRED_BYTES ((size_t)Bb * Pp * Tt * sizeof(float))   // 134,217,728
#define TRIP_BYTES ((size_t)Bb * Pp * 64 * sizeof(float4))  //   8,388,608

// ============================ Phase 1: GEMM =================================
// pred[b][p][t] = data[b,p,:] . W[:,t], W[d][t] = task_pool[t*64+d].
// M=8192 rows (b*256+p), N=4096 cols (t), K=64 (whole K, no k-tiling).
// fp32 VALU (no fp32 MFMA on CDNA4). BM=BN=128, 256 thr, TM=8, TN=4+4.
// acc[8][8] is loop-carried through the k-loop -> the one pattern the RA
// reliably keeps in VGPRs (R1-R5 showed loop-INVARIANT arrays get spilled).
// LDS: As/Bs transposed to [k][*]; inner-loop reads are 16-lane-broadcast
// (free) with <=4-way bank aliasing; A-staging scatter has 16-way conflicts
// but is amortized over 64 k-steps (~10% of block time).
__global__ __launch_bounds__(256, 2) void k_gemm(const float* __restrict__ A,
                                                 const float* __restrict__ Wt,
                                                 float* __restrict__ C) {
  __shared__ float As[Dd][128];   // [k][m] 32 KB
  __shared__ float Bs[Dd][128];   // [k][n] 32 KB
  const int tid = threadIdx.x;
  const int bm  = blockIdx.x * 128;
  const int bn  = blockIdx.y * 128;

  // stage A (transpose [m][k] -> [k][m]); global reads coalesced along k
  {
    const int k0 = (tid & 15) * 4;
    const int r0 = tid >> 4;
#pragma unroll
    for (int l = 0; l < 8; ++l) {
      const int r = r0 + l * 16;
      const float4 v = *(const float4*)(A + (size_t)(bm + r) * Dd + k0);
      As[k0 + 0][r] = v.x; As[k0 + 1][r] = v.y;
      As[k0 + 2][r] = v.z; As[k0 + 3][r] = v.w;
    }
  }
  // stage B: task_pool rows (one task = 64 contiguous floats) -> Bs[k][n]
  {
    const int tt = tid >> 1;
    const int h  = (tid & 1) * 32;
    const float* src = Wt + (size_t)(bn + tt) * Dd + h;
#pragma unroll
    for (int i = 0; i < 8; ++i) {
      const float4 v = *(const float4*)(src + i * 4);
      const int k = h + i * 4;
      Bs[k + 0][tt] = v.x; Bs[k + 1][tt] = v.y;
      Bs[k + 2][tt] = v.z; Bs[k + 3][tt] = v.w;
    }
  }
  __syncthreads();

  const int tm8 = (tid >> 4) * 8;   // 16 m-groups
  const int tn4 = (tid & 15) * 4;   // 16 n-groups, cols {tn4..+3} U {64+tn4..+3}

  float acc[8][8];
#pragma unroll
  for (int i = 0; i < 8; ++i)
#pragma unroll
    for (int j = 0; j < 8; ++j) acc[i][j] = 0.f;

#pragma unroll 8
  for (int k = 0; k < Dd; ++k) {
    float a[8], bv[8];
    *(float4*)&a[0]  = *(const float4*)&As[k][tm8];
    *(float4*)&a[4]  = *(const float4*)&As[k][tm8 + 4];
    *(float4*)&bv[0] = *(const float4*)&Bs[k][tn4];
    *(float4*)&bv[4] = *(const float4*)&Bs[k][64 + tn4];
#pragma unroll
    for (int i = 0; i < 8; ++i)
#pragma unroll
      for (int j = 0; j < 8; ++j) acc[i][j] = fmaf(a[i], bv[j], acc[i][j]);
  }

#pragma unroll
  for (int i = 0; i < 8; ++i) {
    float* crow = C + (size_t)(bm + tm8 + i) * Tt + bn;
    *(float4*)(crow + tn4)      = make_float4(acc[i][0], acc[i][1], acc[i][2], acc[i][3]);
    *(float4*)(crow + 64 + tn4) = make_float4(acc[i][4], acc[i][5], acc[i][6], acc[i][7]);
  }
}

// ============================ Phase 2: scan =================================
// One wave per (b, 64-task chunk) = 2048 waves. Streams pred rows (coalesced
// 256 B/wave/p, batched 8 deep so vmcnt hides L2/L3 latency). Exact per-step
// wave max (R3: any stale shift underflows ALL lanes -> S=0 -> NaN).
// triples: float4 (m, s, v, pad) at [((b*P + p)*64 + chunk)].
__global__ __launch_bounds__(256) void k_scan2(const float* __restrict__ pred,
                                               const float* __restrict__ targets,
                                               float4* __restrict__ triples) {
  const int b     = blockIdx.x >> 4;
  const int wid   = threadIdx.x >> 6;
  const int lane  = threadIdx.x & 63;
  const int chunk = ((blockIdx.x & 15) << 2) | wid;

  const float* __restrict__ base = pred + (size_t)b * Pp * Tt + (chunk << 6) + lane;
  const float* __restrict__ tgt  = targets + b * Pp;
  float4* __restrict__ trb       = triples + (size_t)b * (Pp * 64);

  float c = 0.f;
#pragma unroll 1
  for (int p0 = 0; p0 < Pp; p0 += 8) {
    float pr[8];
#pragma unroll
    for (int j = 0; j < 8; ++j) pr[j] = base[(size_t)(p0 + j) * Tt];
#pragma unroll
    for (int j = 0; j < 8; ++j) {
      const int p = p0 + j;
      float m = c;
#pragma unroll
      for (int off = 32; off; off >>= 1) m = fmaxf(m, __shfl_xor(m, off, 64));
      const float e = __expf(c - m);   // in (0,1], ==1 at the max lane
      float s = e, v = e * pr[j];
#pragma unroll
      for (int off = 32; off; off >>= 1) {
        s += __shfl_xor(s, off, 64);
        v += __shfl_xor(v, off, 64);
      }
      if (lane == 0) trb[p * 64 + chunk] = make_float4(m, s, v, 0.f);
      const float err = tgt[p] - pr[j];
      c = fmaf(-0.5f * err, err, c);
    }
  }
}

// ============================ Phase 3: merge ================================
__global__ __launch_bounds__(256) void k_merge(const float4* __restrict__ ws,
                                               float* __restrict__ out) {
  const int gt   = blockIdx.x * 256 + threadIdx.x;
  const int bp   = gt >> 6;
  const int lane = gt & 63;
  const float4 o = ws[(size_t)bp * 64 + lane];
  const float m = o.x, s = o.y, v = o.z;
  float M = m;
#pragma unroll
  for (int off = 32; off; off >>= 1) M = fmaxf(M, __shfl_xor(M, off, 64));
  const float f = __expf(m - M);
  float S = f * s, V = f * v;
#pragma unroll
  for (int off = 32; off; off >>= 1) {
    S += __shfl_xor(S, off, 64);
    V += __shfl_xor(V, off, 64);
  }
  if (lane == 0) out[bp] = V / S;
}

// ================== Fallback (ws too small): fused R1 =======================
__global__ __launch_bounds__(256) void k_scan_fused(const float* __restrict__ data,
                                                    const float* __restrict__ targets,
                                                    const float* __restrict__ task_pool,
                                                    float4* __restrict__ ws) {
  const int b     = blockIdx.x >> 4;
  const int wid   = threadIdx.x >> 6;
  const int lane  = threadIdx.x & 63;
  const int chunk = ((blockIdx.x & 15) << 2) | wid;
  const int t     = (chunk << 6) | lane;

  float w[Dd];
#pragma unroll
  for (int d = 0; d < Dd; d += 4) {
    const float4 r = *(const float4*)(task_pool + (size_t)t * Dd + d);
    w[d] = r.x; w[d + 1] = r.y; w[d + 2] = r.z; w[d + 3] = r.w;
  }
  const float* __restrict__ drow = data + (size_t)b * (Pp * Dd);
  const float* __restrict__ tgt  = targets + b * Pp;
  float4* __restrict__ wsb       = ws + (size_t)b * (Pp * 64);

  float c = 0.f;
  for (int p = 0; p < Pp; ++p) {
    float a0 = 0.f, a1 = 0.f, a2 = 0.f, a3 = 0.f;
    const float* __restrict__ r = drow + p * Dd;
#pragma unroll
    for (int d = 0; d < Dd; d += 4) {
      a0 = fmaf(r[d], w[d], a0);     a1 = fmaf(r[d + 1], w[d + 1], a1);
      a2 = fmaf(r[d + 2], w[d + 2], a2); a3 = fmaf(r[d + 3], w[d + 3], a3);
    }
    const float pred = (a0 + a1) + (a2 + a3);
    float m = c;
#pragma unroll
    for (int off = 32; off; off >>= 1) m = fmaxf(m, __shfl_xor(m, off, 64));
    const float e = __expf(c - m);
    float s = e, v = e * pred;
#pragma unroll
    for (int off = 32; off; off >>= 1) {
      s += __shfl_xor(s, off, 64);
      v += __shfl_xor(v, off, 64);
    }
    if (lane == 0) wsb[p * 64 + chunk] = make_float4(m, s, v, 0.f);
    const float err = tgt[p] - pred;
    c = fmaf(-0.5f * err, err, c);
  }
}

extern "C" void kernel_launch(void* const* d_in, const int* in_sizes, int n_in,
                              void* d_out, int out_size, void* d_ws, size_t ws_size,
                              hipStream_t stream) {
  const float* data      = (const float*)d_in[0];
  const float* targets   = (const float*)d_in[1];
  const float* task_pool = (const float*)d_in[2];
  float* out = (float*)d_out;

  if (ws_size >= PRED_BYTES + TRIP_BYTES) {
    float*  pred    = (float*)d_ws;
    float4* triples = (float4*)((char*)d_ws + PRED_BYTES);
    k_gemm <<<dim3(8192 / 128, Tt / 128), dim3(256), 0, stream>>>(data, task_pool, pred);
    k_scan2<<<dim3(512),  dim3(256), 0, stream>>>(pred, targets, triples);
    k_merge<<<dim3((Bb * Pp * 64) / 256), dim3(256), 0, stream>>>(triples, out);
  } else {
    float4* triples = (float4*)d_ws;   // 8.4 MB, proven available (R2/R4/R5)
    k_scan_fused<<<dim3(512), dim3(256), 0, stream>>>(data, targets, task_pool, triples);
    k_merge<<<dim3((Bb * Pp * 64) / 256), dim3(256), 0, stream>>>(triples, out);
  }
}

// Round 7
// 220.119 us; speedup vs baseline: 1.6366x; 1.1120x over previous
//
#include <hip/hip_runtime.h>
#include <math.h>

// Problem constants (reference: B=32, P=256, D=64, T=4096, SCALE=1)
#define Bb 32
#define Pp 256
#define Dd 64
#define Tt 4096

#define PRED_BYTES ((size_t)Bb * Pp * Tt * sizeof(float))   // 134,217,728
#define TRIP_BYTES ((size_t)Bb * Pp * 64 * sizeof(float4))  //   8,388,608
#define SEG_BYTES  ((size_t)Bb * 8 * Tt * sizeof(float))    //   4,194,304

// ============================ Phase 1: GEMM =================================
// pred[b][p][t] = data[b,p,:] . W[:,t].  M=8192 (b*256+p), N=4096 (t), K=64.
// fp32 VALU (no fp32 MFMA on CDNA4). BM=BN=128, 256 thr, TM=8, TN=4+4,
// acc[8][8] loop-carried (the pattern RA keeps in VGPRs; R1-R5: loop-invariant
// arrays get spilled no matter what).
// EPILOGUE (R7): wave w of this block owns score rows 32w..32w+31 = exactly
// one 32-p segment of one b (bm = b*256 + (blockIdx.x&1)*128). Computes
// seg_sum[b][seg][t] = sum_{p in seg} -0.5*(tgt[p]-pred[p][t])^2 via two
// shfl_xor(16/32) over the 4 row-groups — feeds the hierarchical scan.
__global__ __launch_bounds__(256, 2) void k_gemm(const float* __restrict__ A,
                                                 const float* __restrict__ Wt,
                                                 const float* __restrict__ targets,
                                                 float* __restrict__ C,
                                                 float* __restrict__ seg_sum) {
  __shared__ float As[Dd][128];   // [k][m] 32 KB
  __shared__ float Bs[Dd][128];   // [k][n] 32 KB
  const int tid = threadIdx.x;
  const int bm  = blockIdx.x * 128;
  const int bn  = blockIdx.y * 128;

  // stage A (transpose [m][k] -> [k][m]); global reads coalesced along k
  {
    const int k0 = (tid & 15) * 4;
    const int r0 = tid >> 4;
#pragma unroll
    for (int l = 0; l < 8; ++l) {
      const int r = r0 + l * 16;
      const float4 v = *(const float4*)(A + (size_t)(bm + r) * Dd + k0);
      As[k0 + 0][r] = v.x; As[k0 + 1][r] = v.y;
      As[k0 + 2][r] = v.z; As[k0 + 3][r] = v.w;
    }
  }
  // stage B: task_pool rows (one task = 64 contiguous floats) -> Bs[k][n]
  {
    const int tt = tid >> 1;
    const int h  = (tid & 1) * 32;
    const float* src = Wt + (size_t)(bn + tt) * Dd + h;
#pragma unroll
    for (int i = 0; i < 8; ++i) {
      const float4 v = *(const float4*)(src + i * 4);
      const int k = h + i * 4;
      Bs[k + 0][tt] = v.x; Bs[k + 1][tt] = v.y;
      Bs[k + 2][tt] = v.z; Bs[k + 3][tt] = v.w;
    }
  }
  __syncthreads();

  const int tm8 = (tid >> 4) * 8;   // 16 m-groups (8 consecutive rows each)
  const int tn4 = (tid & 15) * 4;   // cols {tn4..+3} U {64+tn4..+3}

  float acc[8][8];
#pragma unroll
  for (int i = 0; i < 8; ++i)
#pragma unroll
    for (int j = 0; j < 8; ++j) acc[i][j] = 0.f;

#pragma unroll 8
  for (int k = 0; k < Dd; ++k) {
    float a[8], bv[8];
    *(float4*)&a[0]  = *(const float4*)&As[k][tm8];
    *(float4*)&a[4]  = *(const float4*)&As[k][tm8 + 4];
    *(float4*)&bv[0] = *(const float4*)&Bs[k][tn4];
    *(float4*)&bv[4] = *(const float4*)&Bs[k][64 + tn4];
#pragma unroll
    for (int i = 0; i < 8; ++i)
#pragma unroll
      for (int j = 0; j < 8; ++j) acc[i][j] = fmaf(a[i], bv[j], acc[i][j]);
  }

#pragma unroll
  for (int i = 0; i < 8; ++i) {
    float* crow = C + (size_t)(bm + tm8 + i) * Tt + bn;
    *(float4*)(crow + tn4)      = make_float4(acc[i][0], acc[i][1], acc[i][2], acc[i][3]);
    *(float4*)(crow + 64 + tn4) = make_float4(acc[i][4], acc[i][5], acc[i][6], acc[i][7]);
  }

  // ---- epilogue: per-segment score sums (wave w owns segment w of this tile)
  float trow[8];
  *(float4*)&trow[0] = *(const float4*)(targets + bm + tm8);
  *(float4*)&trow[4] = *(const float4*)(targets + bm + tm8 + 4);
  float sseg[8];
#pragma unroll
  for (int j = 0; j < 8; ++j) {
    float s = 0.f;
#pragma unroll
    for (int i = 0; i < 8; ++i) {
      const float e = trow[i] - acc[i][j];
      s = fmaf(-0.5f * e, e, s);
    }
    sseg[j] = s;
  }
#pragma unroll
  for (int j = 0; j < 8; ++j) {   // reduce over the 4 row-groups of the segment
    sseg[j] += __shfl_xor(sseg[j], 16, 64);
    sseg[j] += __shfl_xor(sseg[j], 32, 64);
  }
  const int lane = tid & 63, w = tid >> 6;
  if (lane < 16) {
    const int b   = blockIdx.x >> 1;
    const int seg = ((blockIdx.x & 1) << 2) | w;
    float* dst = seg_sum + (size_t)(b * 8 + seg) * Tt + bn;
    *(float4*)(dst + tn4)      = make_float4(sseg[0], sseg[1], sseg[2], sseg[3]);
    *(float4*)(dst + 64 + tn4) = make_float4(sseg[4], sseg[5], sseg[6], sseg[7]);
  }
}

// ================= Phase 2a: exclusive scan of segment sums =================
// thread per (b,t): in-place exclusive scan over the 8 segments (stride Tt ->
// coalesced across t). 131072 threads.
__global__ __launch_bounds__(256) void k_segscan(float* __restrict__ seg) {
  const int gt = blockIdx.x * 256 + threadIdx.x;
  const int b  = gt >> 12;
  const int t  = gt & (Tt - 1);
  float* col = seg + (size_t)b * 8 * Tt + t;
  float run = 0.f;
#pragma unroll
  for (int s = 0; s < 8; ++s) {
    const float v = col[(size_t)s * Tt];
    col[(size_t)s * Tt] = run;
    run += v;
  }
}

// ===================== Phase 2b: per-segment scan ===========================
// Wave per (b, chunk, seg): 32*64*8 = 16384 waves (4x R6's occupancy -> the
// 18-deep shuffle chains finally latency-hide; R6's k_scan2 was 2048 waves =
// 22% occupancy, VALUBusy 18%, 136 us). Each wave scans 32 p from seg_base.
// Exact per-step wave max REQUIRED (R3: stale shift -> all-lane underflow ->
// S=0 -> NaN). Triples stores batched: one exec-toggle per 8 p.
__global__ __launch_bounds__(256) void k_scan3(const float* __restrict__ pred,
                                               const float* __restrict__ targets,
                                               const float* __restrict__ segbase,
                                               float4* __restrict__ triples) {
  const int wid  = threadIdx.x >> 6;
  const int lane = threadIdx.x & 63;
  const int W    = blockIdx.x * 4 + wid;     // 0..16383
  const int b     = W >> 9;
  const int chunk = (W >> 3) & 63;
  const int seg   = W & 7;
  const int t     = (chunk << 6) | lane;

  const float* __restrict__ base = pred + (size_t)b * Pp * Tt + t;
  const float* __restrict__ tgt  = targets + b * Pp;
  float4* __restrict__ trb       = triples + (size_t)b * (Pp * 64);

  float c = segbase[(size_t)(b * 8 + seg) * Tt + t];   // exclusive prefix
  const int pstart = seg << 5;
#pragma unroll 1
  for (int p0 = pstart; p0 < pstart + 32; p0 += 8) {
    float pr[8];
#pragma unroll
    for (int j = 0; j < 8; ++j) pr[j] = base[(size_t)(p0 + j) * Tt];
    float sm[8], ss[8], sv[8];
#pragma unroll
    for (int j = 0; j < 8; ++j) {
      float m = c;
#pragma unroll
      for (int off = 32; off; off >>= 1) m = fmaxf(m, __shfl_xor(m, off, 64));
      const float e = __expf(c - m);   // in (0,1], ==1 at the max lane
      float s = e, v = e * pr[j];
#pragma unroll
      for (int off = 32; off; off >>= 1) {
        s += __shfl_xor(s, off, 64);
        v += __shfl_xor(v, off, 64);
      }
      sm[j] = m; ss[j] = s; sv[j] = v;
      const float err = tgt[p0 + j] - pr[j];
      c = fmaf(-0.5f * err, err, c);
    }
    if (lane == 0) {
#pragma unroll
      for (int j = 0; j < 8; ++j)
        trb[(p0 + j) * 64 + chunk] = make_float4(sm[j], ss[j], sv[j], 0.f);
    }
  }
}

// ============================ Phase 3: merge ================================
__global__ __launch_bounds__(256) void k_merge(const float4* __restrict__ ws,
                                               float* __restrict__ out) {
  const int gt   = blockIdx.x * 256 + threadIdx.x;
  const int bp   = gt >> 6;
  const int lane = gt & 63;
  const float4 o = ws[(size_t)bp * 64 + lane];
  const float m = o.x, s = o.y, v = o.z;
  float M = m;
#pragma unroll
  for (int off = 32; off; off >>= 1) M = fmaxf(M, __shfl_xor(M, off, 64));
  const float f = __expf(m - M);
  float S = f * s, V = f * v;
#pragma unroll
  for (int off = 32; off; off >>= 1) {
    S += __shfl_xor(S, off, 64);
    V += __shfl_xor(V, off, 64);
  }
  if (lane == 0) out[bp] = V / S;
}

// ============== Fallback A (no seg buffer): R6 monolithic scan ==============
__global__ __launch_bounds__(256) void k_scan2(const float* __restrict__ pred,
                                               const float* __restrict__ targets,
                                               float4* __restrict__ triples) {
  const int b     = blockIdx.x >> 4;
  const int wid   = threadIdx.x >> 6;
  const int lane  = threadIdx.x & 63;
  const int chunk = ((blockIdx.x & 15) << 2) | wid;

  const float* __restrict__ base = pred + (size_t)b * Pp * Tt + (chunk << 6) + lane;
  const float* __restrict__ tgt  = targets + b * Pp;
  float4* __restrict__ trb       = triples + (size_t)b * (Pp * 64);

  float c = 0.f;
#pragma unroll 1
  for (int p0 = 0; p0 < Pp; p0 += 8) {
    float pr[8];
#pragma unroll
    for (int j = 0; j < 8; ++j) pr[j] = base[(size_t)(p0 + j) * Tt];
#pragma unroll
    for (int j = 0; j < 8; ++j) {
      const int p = p0 + j;
      float m = c;
#pragma unroll
      for (int off = 32; off; off >>= 1) m = fmaxf(m, __shfl_xor(m, off, 64));
      const float e = __expf(c - m);
      float s = e, v = e * pr[j];
#pragma unroll
      for (int off = 32; off; off >>= 1) {
        s += __shfl_xor(s, off, 64);
        v += __shfl_xor(v, off, 64);
      }
      if (lane == 0) trb[p * 64 + chunk] = make_float4(m, s, v, 0.f);
      const float err = tgt[p] - pr[j];
      c = fmaf(-0.5f * err, err, c);
    }
  }
}

// ============== Fallback B (tiny ws): fused R1 structure ====================
__global__ __launch_bounds__(256) void k_scan_fused(const float* __restrict__ data,
                                                    const float* __restrict__ targets,
                                                    const float* __restrict__ task_pool,
                                                    float4* __restrict__ ws) {
  const int b     = blockIdx.x >> 4;
  const int wid   = threadIdx.x >> 6;
  const int lane  = threadIdx.x & 63;
  const int chunk = ((blockIdx.x & 15) << 2) | wid;
  const int t     = (chunk << 6) | lane;

  float w[Dd];
#pragma unroll
  for (int d = 0; d < Dd; d += 4) {
    const float4 r = *(const float4*)(task_pool + (size_t)t * Dd + d);
    w[d] = r.x; w[d + 1] = r.y; w[d + 2] = r.z; w[d + 3] = r.w;
  }
  const float* __restrict__ drow = data + (size_t)b * (Pp * Dd);
  const float* __restrict__ tgt  = targets + b * Pp;
  float4* __restrict__ wsb       = ws + (size_t)b * (Pp * 64);

  float c = 0.f;
  for (int p = 0; p < Pp; ++p) {
    float a0 = 0.f, a1 = 0.f, a2 = 0.f, a3 = 0.f;
    const float* __restrict__ r = drow + p * Dd;
#pragma unroll
    for (int d = 0; d < Dd; d += 4) {
      a0 = fmaf(r[d], w[d], a0);         a1 = fmaf(r[d + 1], w[d + 1], a1);
      a2 = fmaf(r[d + 2], w[d + 2], a2); a3 = fmaf(r[d + 3], w[d + 3], a3);
    }
    const float pred = (a0 + a1) + (a2 + a3);
    float m = c;
#pragma unroll
    for (int off = 32; off; off >>= 1) m = fmaxf(m, __shfl_xor(m, off, 64));
    const float e = __expf(c - m);
    float s = e, v = e * pred;
#pragma unroll
    for (int off = 32; off; off >>= 1) {
      s += __shfl_xor(s, off, 64);
      v += __shfl_xor(v, off, 64);
    }
    if (lane == 0) wsb[p * 64 + chunk] = make_float4(m, s, v, 0.f);
    const float err = tgt[p] - pred;
    c = fmaf(-0.5f * err, err, c);
  }
}

extern "C" void kernel_launch(void* const* d_in, const int* in_sizes, int n_in,
                              void* d_out, int out_size, void* d_ws, size_t ws_size,
                              hipStream_t stream) {
  const float* data      = (const float*)d_in[0];
  const float* targets   = (const float*)d_in[1];
  const float* task_pool = (const float*)d_in[2];
  float* out = (float*)d_out;

  if (ws_size >= PRED_BYTES + TRIP_BYTES + SEG_BYTES) {
    float*  pred    = (float*)d_ws;
    float4* triples = (float4*)((char*)d_ws + PRED_BYTES);
    float*  seg     = (float*)((char*)d_ws + PRED_BYTES + TRIP_BYTES);
    k_gemm   <<<dim3(8192 / 128, Tt / 128), dim3(256), 0, stream>>>(data, task_pool, targets, pred, seg);
    k_segscan<<<dim3(Bb * Tt / 256), dim3(256), 0, stream>>>(seg);
    k_scan3  <<<dim3(4096), dim3(256), 0, stream>>>(pred, targets, seg, triples);
    k_merge  <<<dim3((Bb * Pp * 64) / 256), dim3(256), 0, stream>>>(triples, out);
  } else if (ws_size >= PRED_BYTES + TRIP_BYTES) {
    // R6 path (no seg buffer): gemm without epilogue target isn't compiled
    // separately; reuse k_gemm writing seg into the triples area is unsafe, so
    // fall back to the proven monolithic scan. seg_sum is written into the
    // first 4 MB of triples? NO — keep it simple: dummy seg target = triples
    // region is unsafe; use scan2 which needs no seg buffer.
    float*  pred    = (float*)d_ws;
    float4* triples = (float4*)((char*)d_ws + PRED_BYTES);
    // k_gemm needs a seg_sum pointer; reuse the last 4 MB of pred? pred is
    // fully used. Allocate seg inside triples is racy with scan2? scan2 never
    // reads seg — but k_gemm would overwrite triples before scan2 writes them.
    // Order is sequential on one stream: k_gemm writes garbage seg into the
    // triples area, THEN scan2/merge overwrite/consume triples. Safe.
    float* seg_alias = (float*)triples;   // 4 MB < TRIP_BYTES, overwritten later
    k_gemm <<<dim3(8192 / 128, Tt / 128), dim3(256), 0, stream>>>(data, task_pool, targets, pred, seg_alias);
    k_scan2<<<dim3(512), dim3(256), 0, stream>>>(pred, targets, triples);
    k_merge<<<dim3((Bb * Pp * 64) / 256), dim3(256), 0, stream>>>(triples, out);
  } else {
    float4* triples = (float4*)d_ws;
    k_scan_fused<<<dim3(512), dim3(256), 0, stream>>>(data, targets, task_pool, triples);
    k_merge<<<dim3((Bb * Pp * 64) / 256), dim3(256), 0, stream>>>(triples, out);
  }
}

// Round 8
// 159.191 us; speedup vs baseline: 2.2630x; 1.3827x over previous
//
#include <hip/hip_runtime.h>
#include <math.h>

// Problem constants (reference: B=32, P=256, D=64, T=4096, SCALE=1)
#define Bb 32
#define Pp 256
#define Dd 64
#define Tt 4096

#define PRED_BYTES  ((size_t)Bb * Pp * Tt * sizeof(float))   // 134,217,728
#define SEG32_BYTES ((size_t)Bb * 32 * Tt * sizeof(float))   //  16,777,216
#define SEG16_BYTES ((size_t)Bb * 16 * Tt * sizeof(float))   //   8,388,608
#define TRIP_BYTES  ((size_t)Bb * Pp * 64 * sizeof(float4))  //   8,388,608

// ============================ Phase 1: GEMM =================================
// pred[b][p][t] = data[b,p,:] . W[:,t].  M=8192 (b*256+p), N=4096 (t), K=64.
// fp32 VALU (no fp32 MFMA on CDNA4). BM=BN=128, 256 thr, TM=8, TN=4+4,
// acc[8][8] loop-carried (R1-R5: only loop-carried arrays stay in VGPRs).
// EPILOGUE (R8): each thread owns 8 CONSECUTIVE rows x 8 cols, so an 8-row
// p-segment sum needs NO shuffles (nseg=32); nseg=16 needs one shfl_xor(16).
// seg_sum[b][seg][t] = sum_{p in seg} -0.5*(tgt[p]-pred[p][t])^2.
__global__ __launch_bounds__(256, 2) void k_gemm(const float* __restrict__ A,
                                                 const float* __restrict__ Wt,
                                                 const float* __restrict__ targets,
                                                 float* __restrict__ C,
                                                 float* __restrict__ seg_sum,
                                                 int nseg) {
  __shared__ float As[Dd][128];   // [k][m] 32 KB
  __shared__ float Bs[Dd][128];   // [k][n] 32 KB
  const int tid = threadIdx.x;
  const int bm  = blockIdx.x * 128;
  const int bn  = blockIdx.y * 128;

  // stage A (transpose [m][k] -> [k][m]); global reads coalesced along k
  {
    const int k0 = (tid & 15) * 4;
    const int r0 = tid >> 4;
#pragma unroll
    for (int l = 0; l < 8; ++l) {
      const int r = r0 + l * 16;
      const float4 v = *(const float4*)(A + (size_t)(bm + r) * Dd + k0);
      As[k0 + 0][r] = v.x; As[k0 + 1][r] = v.y;
      As[k0 + 2][r] = v.z; As[k0 + 3][r] = v.w;
    }
  }
  // stage B: task_pool rows (one task = 64 contiguous floats) -> Bs[k][n]
  {
    const int tt = tid >> 1;
    const int h  = (tid & 1) * 32;
    const float* src = Wt + (size_t)(bn + tt) * Dd + h;
#pragma unroll
    for (int i = 0; i < 8; ++i) {
      const float4 v = *(const float4*)(src + i * 4);
      const int k = h + i * 4;
      Bs[k + 0][tt] = v.x; Bs[k + 1][tt] = v.y;
      Bs[k + 2][tt] = v.z; Bs[k + 3][tt] = v.w;
    }
  }
  __syncthreads();

  const int tm8 = (tid >> 4) * 8;   // 16 m-groups (8 consecutive rows each)
  const int tn4 = (tid & 15) * 4;   // cols {tn4..+3} U {64+tn4..+3}

  float acc[8][8];
#pragma unroll
  for (int i = 0; i < 8; ++i)
#pragma unroll
    for (int j = 0; j < 8; ++j) acc[i][j] = 0.f;

#pragma unroll 8
  for (int k = 0; k < Dd; ++k) {
    float a[8], bv[8];
    *(float4*)&a[0]  = *(const float4*)&As[k][tm8];
    *(float4*)&a[4]  = *(const float4*)&As[k][tm8 + 4];
    *(float4*)&bv[0] = *(const float4*)&Bs[k][tn4];
    *(float4*)&bv[4] = *(const float4*)&Bs[k][64 + tn4];
#pragma unroll
    for (int i = 0; i < 8; ++i)
#pragma unroll
      for (int j = 0; j < 8; ++j) acc[i][j] = fmaf(a[i], bv[j], acc[i][j]);
  }

#pragma unroll
  for (int i = 0; i < 8; ++i) {
    float* crow = C + (size_t)(bm + tm8 + i) * Tt + bn;
    *(float4*)(crow + tn4)      = make_float4(acc[i][0], acc[i][1], acc[i][2], acc[i][3]);
    *(float4*)(crow + 64 + tn4) = make_float4(acc[i][4], acc[i][5], acc[i][6], acc[i][7]);
  }

  // ---- epilogue: per-segment score sums (thread-local over its 8 rows)
  float trow[8];
  *(float4*)&trow[0] = *(const float4*)(targets + bm + tm8);
  *(float4*)&trow[4] = *(const float4*)(targets + bm + tm8 + 4);
  float s8[8];
#pragma unroll
  for (int j = 0; j < 8; ++j) {
    float s = 0.f;
#pragma unroll
    for (int i = 0; i < 8; ++i) {
      const float e = trow[i] - acc[i][j];
      s = fmaf(-0.5f * e, e, s);
    }
    s8[j] = s;
  }
  const int grow = bm + tm8;        // first global row this thread owns
  const int b    = grow >> 8;
  if (nseg == 32) {
    const int sg = (grow >> 3) & 31;
    float* dst = seg_sum + ((size_t)(b * 32 + sg)) * Tt + bn;
    *(float4*)(dst + tn4)      = make_float4(s8[0], s8[1], s8[2], s8[3]);
    *(float4*)(dst + 64 + tn4) = make_float4(s8[4], s8[5], s8[6], s8[7]);
  } else {  // nseg == 16: combine the two 8-row halves (lanes tid ^ 16)
#pragma unroll
    for (int j = 0; j < 8; ++j) s8[j] += __shfl_xor(s8[j], 16, 64);
    if (!(tid & 16)) {
      const int sg = (grow >> 4) & 15;
      float* dst = seg_sum + ((size_t)(b * 16 + sg)) * Tt + bn;
      *(float4*)(dst + tn4)      = make_float4(s8[0], s8[1], s8[2], s8[3]);
      *(float4*)(dst + 64 + tn4) = make_float4(s8[4], s8[5], s8[6], s8[7]);
    }
  }
}

// ================= Phase 2a: exclusive scan of segment sums =================
// thread per (b,t): in-place exclusive scan over nseg segments (stride Tt).
__global__ __launch_bounds__(256) void k_segscan(float* __restrict__ seg, int nseg) {
  const int gt = blockIdx.x * 256 + threadIdx.x;
  const int b  = gt >> 12;
  const int t  = gt & (Tt - 1);
  float* col = seg + (size_t)b * nseg * Tt + t;
  float run = 0.f;
  for (int s = 0; s < nseg; ++s) {
    const float v = col[(size_t)s * Tt];
    col[(size_t)s * Tt] = run;
    run += v;
  }
}

// ===================== Phase 2b: transposed scan ============================
// R7 post-mortem: k_scan3 was LDS-PIPE-THROUGHPUT bound — 16384 waves x 32 p
// x 18 shuffles = 9.4M wave-swizzles ≈ 89 us alone. Fix: transpose ownership.
// One wave owns ALL 4096 t for its (b, 8-p segment); lane l holds t=i*64+l,
// i<64, as c[64] LOOP-CARRIED registers (the RA-friendly pattern). Per p:
// per-lane two-pass (reg-tree max, then exp+accumulate) and only ONE 18-
// shuffle cross-lane merge -> 64x fewer shuffles per (b,p). Writes out[b,p]
// directly: triples + merge phases deleted.
// Shift safety (R3): e=exp(c-m_l)<=1; f=exp(m_l-M)<=1, f==1 at argmax lane
// so S>=1 — no all-lane underflow.
template <int NSEG>
__global__ __launch_bounds__(64, 1) void k_scan4(const float* __restrict__ pred,
                                                 const float* __restrict__ targets,
                                                 const float* __restrict__ segbase,
                                                 float* __restrict__ out) {
  constexpr int PSEG = Pp / NSEG;
  const int W    = blockIdx.x;          // b*NSEG + seg
  const int b    = W / NSEG;
  const int seg  = W % NSEG;
  const int lane = threadIdx.x;         // 0..63

  // init c[i] = exclusive prefix for t = i*64+lane (coalesced 256B loads)
  float c[64];
  {
    const float* sb = segbase + (size_t)(b * NSEG + seg) * Tt + lane;
#pragma unroll
    for (int i = 0; i < 64; ++i) c[i] = sb[i * 64];
  }

  const float* __restrict__ pb  = pred + (size_t)b * Pp * Tt + (size_t)(seg * PSEG) * Tt + lane;
  const float* __restrict__ tg  = targets + b * Pp + seg * PSEG;
  float* __restrict__ ob        = out + b * Pp + seg * PSEG;

#pragma unroll 1
  for (int p = 0; p < PSEG; ++p) {
    // load this p's pred row slice (64 coalesced loads, issued up front)
    float pr[64];
    {
      const float* pp = pb + (size_t)p * Tt;
#pragma unroll
      for (int i = 0; i < 64; ++i) pr[i] = pp[i * 64];
    }

    // per-lane register-tree max of c[64] (depth 6, hides the load latency)
    float mr[32];
#pragma unroll
    for (int i = 0; i < 32; ++i) mr[i] = fmaxf(c[i], c[i + 32]);
#pragma unroll
    for (int i = 0; i < 16; ++i) mr[i] = fmaxf(mr[i], mr[i + 16]);
#pragma unroll
    for (int i = 0; i < 8; ++i)  mr[i] = fmaxf(mr[i], mr[i + 8]);
#pragma unroll
    for (int i = 0; i < 4; ++i)  mr[i] = fmaxf(mr[i], mr[i + 4]);
    const float ml = fmaxf(fmaxf(mr[0], mr[2]), fmaxf(mr[1], mr[3]));

    // per-lane accumulate s,v with shift ml; then update c for next p
    float s = 0.f, v = 0.f;
#pragma unroll
    for (int i = 0; i < 64; ++i) {
      const float e = __expf(c[i] - ml);
      s += e;
      v = fmaf(e, pr[i], v);
    }
    const float tv = tg[p];
#pragma unroll
    for (int i = 0; i < 64; ++i) {
      const float err = tv - pr[i];
      c[i] = fmaf(-0.5f * err, err, c[i]);
    }

    // single cross-lane merge per (b,p)
    float M = ml;
#pragma unroll
    for (int off = 32; off; off >>= 1) M = fmaxf(M, __shfl_xor(M, off, 64));
    const float f = __expf(ml - M);
    float S = f * s, V = f * v;
#pragma unroll
    for (int off = 32; off; off >>= 1) {
      S += __shfl_xor(S, off, 64);
      V += __shfl_xor(V, off, 64);
    }
    if (lane == 0) ob[p] = V / S;
  }
}

// ============== Fallback (tiny ws): fused R1 structure + merge ==============
__global__ __launch_bounds__(256) void k_scan_fused(const float* __restrict__ data,
                                                    const float* __restrict__ targets,
                                                    const float* __restrict__ task_pool,
                                                    float4* __restrict__ ws) {
  const int b     = blockIdx.x >> 4;
  const int wid   = threadIdx.x >> 6;
  const int lane  = threadIdx.x & 63;
  const int chunk = ((blockIdx.x & 15) << 2) | wid;
  const int t     = (chunk << 6) | lane;

  float w[Dd];
#pragma unroll
  for (int d = 0; d < Dd; d += 4) {
    const float4 r = *(const float4*)(task_pool + (size_t)t * Dd + d);
    w[d] = r.x; w[d + 1] = r.y; w[d + 2] = r.z; w[d + 3] = r.w;
  }
  const float* __restrict__ drow = data + (size_t)b * (Pp * Dd);
  const float* __restrict__ tgt  = targets + b * Pp;
  float4* __restrict__ wsb       = ws + (size_t)b * (Pp * 64);

  float c = 0.f;
  for (int p = 0; p < Pp; ++p) {
    float a0 = 0.f, a1 = 0.f, a2 = 0.f, a3 = 0.f;
    const float* __restrict__ r = drow + p * Dd;
#pragma unroll
    for (int d = 0; d < Dd; d += 4) {
      a0 = fmaf(r[d], w[d], a0);         a1 = fmaf(r[d + 1], w[d + 1], a1);
      a2 = fmaf(r[d + 2], w[d + 2], a2); a3 = fmaf(r[d + 3], w[d + 3], a3);
    }
    const float pred = (a0 + a1) + (a2 + a3);
    float m = c;
#pragma unroll
    for (int off = 32; off; off >>= 1) m = fmaxf(m, __shfl_xor(m, off, 64));
    const float e = __expf(c - m);
    float s = e, v = e * pred;
#pragma unroll
    for (int off = 32; off; off >>= 1) {
      s += __shfl_xor(s, off, 64);
      v += __shfl_xor(v, off, 64);
    }
    if (lane == 0) wsb[p * 64 + chunk] = make_float4(m, s, v, 0.f);
    const float err = tgt[p] - pred;
    c = fmaf(-0.5f * err, err, c);
  }
}

__global__ __launch_bounds__(256) void k_merge(const float4* __restrict__ ws,
                                               float* __restrict__ out) {
  const int gt   = blockIdx.x * 256 + threadIdx.x;
  const int bp   = gt >> 6;
  const int lane = gt & 63;
  const float4 o = ws[(size_t)bp * 64 + lane];
  const float m = o.x, s = o.y, v = o.z;
  float M = m;
#pragma unroll
  for (int off = 32; off; off >>= 1) M = fmaxf(M, __shfl_xor(M, off, 64));
  const float f = __expf(m - M);
  float S = f * s, V = f * v;
#pragma unroll
  for (int off = 32; off; off >>= 1) {
    S += __shfl_xor(S, off, 64);
    V += __shfl_xor(V, off, 64);
  }
  if (lane == 0) out[bp] = V / S;
}

extern "C" void kernel_launch(void* const* d_in, const int* in_sizes, int n_in,
                              void* d_out, int out_size, void* d_ws, size_t ws_size,
                              hipStream_t stream) {
  const float* data      = (const float*)d_in[0];
  const float* targets   = (const float*)d_in[1];
  const float* task_pool = (const float*)d_in[2];
  float* out = (float*)d_out;

  if (ws_size >= PRED_BYTES + SEG32_BYTES) {
    float* pred = (float*)d_ws;
    float* seg  = (float*)((char*)d_ws + PRED_BYTES);
    k_gemm   <<<dim3(8192 / 128, Tt / 128), dim3(256), 0, stream>>>(data, task_pool, targets, pred, seg, 32);
    k_segscan<<<dim3(Bb * Tt / 256), dim3(256), 0, stream>>>(seg, 32);
    k_scan4<32><<<dim3(Bb * 32), dim3(64), 0, stream>>>(pred, targets, seg, out);
  } else if (ws_size >= PRED_BYTES + SEG16_BYTES) {
    float* pred = (float*)d_ws;
    float* seg  = (float*)((char*)d_ws + PRED_BYTES);
    k_gemm   <<<dim3(8192 / 128, Tt / 128), dim3(256), 0, stream>>>(data, task_pool, targets, pred, seg, 16);
    k_segscan<<<dim3(Bb * Tt / 256), dim3(256), 0, stream>>>(seg, 16);
    k_scan4<16><<<dim3(Bb * 16), dim3(64), 0, stream>>>(pred, targets, seg, out);
  } else {
    float4* triples = (float4*)d_ws;   // 8.4 MB
    k_scan_fused<<<dim3(512), dim3(256), 0, stream>>>(data, targets, task_pool, triples);
    k_merge<<<dim3((Bb * Pp * 64) / 256), dim3(256), 0, stream>>>(triples, out);
  }
}